// Round 1
// baseline (552.333 us; speedup 1.0000x reference)
//
#include <hip/hip_runtime.h>
#include <math.h>

#define DIMC 96
#define DIN  192
#define NST  16
#define RNK  6
#define KD   4
#define HH   64
#define WWD  64
#define LL   4096
#define BB   2
#define NC   64    // number of chunks
#define CH   64    // chunk length (NC*CH == LL)

__device__ __forceinline__ int pos_of(int k, int l) {
    // direction k's step l reads flat position pos_of(k,l) of the (H,W) grid
    int t = ((l & 63) << 6) | (l >> 6);       // 64x64 transpose
    switch (k) {
        case 0: return l;
        case 1: return t;
        case 2: return LL - 1 - l;
        default: return ((( (LL-1-l) & 63) << 6) | ((LL-1-l) >> 6));
    }
}

__device__ __forceinline__ float silu_f(float v) {
    return v / (1.f + expf(-v));
}

// ---------------- K1: diff = |x-y|, LayerNorm(96), in_proj (384x96) ----------------
__global__ __launch_bounds__(384) void k1_ln_inproj(
    const float* __restrict__ x, const float* __restrict__ y,
    const float* __restrict__ ln_w, const float* __restrict__ ln_b,
    const float* __restrict__ Win,
    float* __restrict__ diff, float* __restrict__ xm, float* __restrict__ zbuf)
{
    int p = blockIdx.x;            // b*L + l, 0..8191
    int t = threadIdx.x;
    __shared__ float h[DIMC];
    __shared__ float red[6], red2[6];
    __shared__ float s_mu, s_rstd;

    float v = 0.f;
    if (t < DIMC) {
        v = fabsf(x[p*DIMC + t] - y[p*DIMC + t]);
        diff[p*DIMC + t] = v;
    }
    float s = v, s2 = v*v;
    #pragma unroll
    for (int off = 32; off > 0; off >>= 1) {
        s  += __shfl_down(s,  off);
        s2 += __shfl_down(s2, off);
    }
    int wid = t >> 6, lane = t & 63;
    if (lane == 0) { red[wid] = s; red2[wid] = s2; }
    __syncthreads();
    if (t == 0) {
        float S = 0.f, S2 = 0.f;
        #pragma unroll
        for (int i = 0; i < 6; i++) { S += red[i]; S2 += red2[i]; }
        float mu  = S / DIMC;
        float var = S2 / DIMC - mu*mu;
        s_mu = mu; s_rstd = rsqrtf(var + 1e-5f);
    }
    __syncthreads();
    if (t < DIMC) h[t] = (v - s_mu) * s_rstd * ln_w[t] + ln_b[t];
    __syncthreads();

    float acc = 0.f;
    const float* wr = Win + t*DIMC;
    #pragma unroll 8
    for (int j = 0; j < DIMC; j++) acc += h[j] * wr[j];
    if (t < DIN) xm[(size_t)p*DIN + t] = acc;
    else         zbuf[(size_t)p*DIN + (t - DIN)] = acc;
}

// ---------------- K2: depthwise 3x3 conv + bias + SiLU ----------------
__global__ __launch_bounds__(192) void k2_conv(
    const float* __restrict__ xm, const float* __restrict__ cw,
    const float* __restrict__ cb, float* __restrict__ xconv)
{
    int p = blockIdx.x;            // b*L + l
    int d = threadIdx.x;
    int b = p >> 12;
    int l = p & (LL - 1);
    int hh = l >> 6, ww = l & 63;
    float acc = cb[d];
    const float* wd = cw + d*9;
    #pragma unroll
    for (int di = -1; di <= 1; di++) {
        int h2 = hh + di;
        if ((unsigned)h2 < HH) {
            #pragma unroll
            for (int dj = -1; dj <= 1; dj++) {
                int w2 = ww + dj;
                if ((unsigned)w2 < WWD)
                    acc += wd[(di+1)*3 + (dj+1)] * xm[((size_t)b*LL + h2*WWD + w2)*DIN + d];
            }
        }
    }
    xconv[(size_t)p*DIN + d] = silu_f(acc);
}

// ---------------- K3: x_proj (38x192) + dt_proj (192x6) + softplus ----------------
__global__ __launch_bounds__(192) void k3_xproj(
    const float* __restrict__ xconv, const float* __restrict__ xpw,
    const float* __restrict__ dtw, const float* __restrict__ dtb,
    float* __restrict__ delta, float* __restrict__ Bs, float* __restrict__ Cs)
{
    int blk = blockIdx.x;          // (b*K + k)*L + l
    int l  = blk & (LL - 1);
    int bk = blk >> 12;
    int k  = bk & 3;
    int b  = bk >> 2;
    int t  = threadIdx.x;
    __shared__ float u[DIN];
    __shared__ float xd[RNK + 2*NST];   // 38

    int pos = pos_of(k, l);
    u[t] = xconv[((size_t)b*LL + pos)*DIN + t];
    __syncthreads();

    int g = t >> 2, sl = t & 3;
    if (g < RNK + 2*NST) {
        const float* wr = xpw + ((size_t)k*(RNK+2*NST) + g)*DIN;
        float a = 0.f;
        for (int j = sl; j < DIN; j += 4) a += u[j] * wr[j];
        a += __shfl_down(a, 2, 4);
        a += __shfl_down(a, 1, 4);
        if (sl == 0) xd[g] = a;
    }
    __syncthreads();

    // delta = softplus(dt_w @ dts + dt_b)
    float acc = dtb[k*DIN + t];
    const float* dw = dtw + ((size_t)k*DIN + t)*RNK;
    #pragma unroll
    for (int r = 0; r < RNK; r++) acc += xd[r] * dw[r];
    float sp = (acc > 20.f) ? acc : log1pf(expf(acc));
    delta[((size_t)bk*LL + l)*DIN + t] = sp;

    if (t < NST)                       Bs[((size_t)bk*LL + l)*NST + t]        = xd[RNK + t];
    else if (t >= 64 && t < 64 + NST)  Cs[((size_t)bk*LL + l)*NST + (t - 64)] = xd[RNK + NST + (t - 64)];
}

// ---------------- K4: scan pass A — per-chunk transfer (P = prod a, Q = local end state) ----------------
__global__ __launch_bounds__(192) void k4_scanA(
    const float* __restrict__ xconv, const float* __restrict__ delta,
    const float* __restrict__ BsArr, const float* __restrict__ A_log,
    float* __restrict__ P, float* __restrict__ Q)
{
    int blk = blockIdx.x;          // (b*K + k)*NC + c
    int c  = blk & (NC - 1);
    int bk = blk >> 6;
    int k  = bk & 3;
    int b  = bk >> 2;
    int d  = threadIdx.x;
    __shared__ float sB[CH][NST];
    for (int i = d; i < CH*NST; i += DIN) {
        int step = i >> 4, n = i & 15;
        sB[step][n] = BsArr[((size_t)bk*LL + c*CH + step)*NST + n];
    }
    float A[NST];
    #pragma unroll
    for (int n = 0; n < NST; n++) A[n] = -expf(A_log[((size_t)k*DIN + d)*NST + n]);
    __syncthreads();

    float h[NST], p[NST];
    #pragma unroll
    for (int n = 0; n < NST; n++) { h[n] = 0.f; p[n] = 1.f; }

    for (int step = 0; step < CH; step++) {
        int l = c*CH + step;
        float dl = delta[((size_t)bk*LL + l)*DIN + d];
        float uu = xconv[((size_t)b*LL + pos_of(k, l))*DIN + d];
        float du = dl * uu;
        #pragma unroll
        for (int n = 0; n < NST; n++) {
            float a = __expf(dl * A[n]);
            h[n] = a*h[n] + du*sB[step][n];
            p[n] *= a;
        }
    }
    size_t base = (size_t)blk*NST*DIN + d;
    #pragma unroll
    for (int n = 0; n < NST; n++) { P[base + n*DIN] = p[n]; Q[base + n*DIN] = h[n]; }
}

// ---------------- K5: scan pass B — compose chunk transfers; Q becomes per-chunk init state ----------------
__global__ __launch_bounds__(256) void k5_scanB(
    const float* __restrict__ P, float* __restrict__ Q)
{
    int idx = blockIdx.x*256 + threadIdx.x;      // 24576 = B*K*N*Din
    if (idx >= BB*KD*NST*DIN) return;
    int d = idx % DIN;
    int rest = idx / DIN;
    int n = rest % NST; rest /= NST;
    int k = rest % KD;
    int b = rest / KD;
    size_t base = ((((size_t)(b*KD + k))*NC)*NST + n)*DIN + d;
    size_t stride = (size_t)NST*DIN;
    float h = 0.f;
    for (int c = 0; c < NC; c++) {
        float p = P[base + c*stride];
        float q = Q[base + c*stride];
        Q[base + c*stride] = h;                  // init state for chunk c
        h = p*h + q;
    }
}

// ---------------- K6: scan pass C — replay with init state, emit y (+ D*u) ----------------
__global__ __launch_bounds__(192) void k6_scanC(
    const float* __restrict__ xconv, const float* __restrict__ delta,
    const float* __restrict__ BsArr, const float* __restrict__ CsArr,
    const float* __restrict__ A_log, const float* __restrict__ Ds,
    const float* __restrict__ Q, float* __restrict__ outy)
{
    int blk = blockIdx.x;          // (b*K + k)*NC + c
    int c  = blk & (NC - 1);
    int bk = blk >> 6;
    int k  = bk & 3;
    int b  = bk >> 2;
    int d  = threadIdx.x;
    __shared__ float sB[CH][NST];
    __shared__ float sC[CH][NST];
    for (int i = d; i < CH*NST; i += DIN) {
        int step = i >> 4, n = i & 15;
        sB[step][n] = BsArr[((size_t)bk*LL + c*CH + step)*NST + n];
        sC[step][n] = CsArr[((size_t)bk*LL + c*CH + step)*NST + n];
    }
    float A[NST];
    #pragma unroll
    for (int n = 0; n < NST; n++) A[n] = -expf(A_log[((size_t)k*DIN + d)*NST + n]);
    float h[NST];
    size_t base = (size_t)blk*NST*DIN + d;
    #pragma unroll
    for (int n = 0; n < NST; n++) h[n] = Q[base + n*DIN];
    float Dv = Ds[k*DIN + d];
    __syncthreads();

    for (int step = 0; step < CH; step++) {
        int l = c*CH + step;
        float dl = delta[((size_t)bk*LL + l)*DIN + d];
        float uu = xconv[((size_t)b*LL + pos_of(k, l))*DIN + d];
        float du = dl * uu;
        float yv = 0.f;
        #pragma unroll
        for (int n = 0; n < NST; n++) {
            float a = __expf(dl * A[n]);
            h[n] = a*h[n] + du*sB[step][n];
            yv += h[n] * sC[step][n];
        }
        outy[((size_t)bk*LL + l)*DIN + d] = yv + Dv*uu;
    }
}

// ---------------- K7: 4-direction combine, LayerNorm(192), gate, out_proj, residual ----------------
__global__ __launch_bounds__(192) void k7_out(
    const float* __restrict__ outy, const float* __restrict__ zbuf,
    const float* __restrict__ diff, const float* __restrict__ onw,
    const float* __restrict__ onb, const float* __restrict__ Wout,
    float* __restrict__ out)
{
    int p = blockIdx.x;            // b*L + l
    int b = p >> 12;
    int l = p & (LL - 1);
    int d = threadIdx.x;
    int tl = ((l & 63) << 6) | (l >> 6);

    __shared__ float g[DIN];
    __shared__ float red[3], red2[3];
    __shared__ float s_mu, s_rstd;

    float yc = outy[(((size_t)(b*KD + 0))*LL + l)*DIN + d]
             + outy[(((size_t)(b*KD + 2))*LL + (LL-1-l))*DIN + d]
             + outy[(((size_t)(b*KD + 1))*LL + tl)*DIN + d]
             + outy[(((size_t)(b*KD + 3))*LL + (LL-1-tl))*DIN + d];

    float s = yc, s2 = yc*yc;
    #pragma unroll
    for (int off = 32; off > 0; off >>= 1) {
        s  += __shfl_down(s,  off);
        s2 += __shfl_down(s2, off);
    }
    int wid = d >> 6, lane = d & 63;
    if (lane == 0) { red[wid] = s; red2[wid] = s2; }
    __syncthreads();
    if (d == 0) {
        float S = red[0]+red[1]+red[2];
        float S2 = red2[0]+red2[1]+red2[2];
        float mu = S / DIN;
        float var = S2 / DIN - mu*mu;
        s_mu = mu; s_rstd = rsqrtf(var + 1e-5f);
    }
    __syncthreads();
    float yn = (yc - s_mu) * s_rstd * onw[d] + onb[d];
    g[d] = yn * silu_f(zbuf[(size_t)p*DIN + d]);
    __syncthreads();

    if (d < DIMC) {
        const float* wr = Wout + d*DIN;
        float acc = diff[(size_t)p*DIMC + d];
        #pragma unroll 8
        for (int j = 0; j < DIN; j++) acc += g[j] * wr[j];
        out[(size_t)p*DIMC + d] = acc;
    }
}

extern "C" void kernel_launch(void* const* d_in, const int* in_sizes, int n_in,
                              void* d_out, int out_size, void* d_ws, size_t ws_size,
                              hipStream_t stream)
{
    const float* x       = (const float*)d_in[0];
    const float* y       = (const float*)d_in[1];
    const float* ln_w    = (const float*)d_in[2];
    const float* ln_b    = (const float*)d_in[3];
    const float* in_proj = (const float*)d_in[4];
    const float* conv_w  = (const float*)d_in[5];
    const float* conv_b  = (const float*)d_in[6];
    const float* x_proj  = (const float*)d_in[7];
    const float* dt_w    = (const float*)d_in[8];
    const float* dt_b    = (const float*)d_in[9];
    const float* A_log   = (const float*)d_in[10];
    const float* Ds      = (const float*)d_in[11];
    const float* onw     = (const float*)d_in[12];
    const float* onb     = (const float*)d_in[13];
    const float* out_w   = (const float*)d_in[14];
    float* out = (float*)d_out;

    float* ws    = (float*)d_ws;
    float* diff  = ws;                       // 786432
    float* zbuf  = diff  + 786432;           // 1572864
    float* xm    = zbuf  + 1572864;          // 1572864
    float* xconv = xm    + 1572864;          // 1572864
    float* delta = xconv + 1572864;          // 6291456
    float* Bs    = delta + 6291456;          // 524288
    float* Cs    = Bs    + 524288;           // 524288
    float* outy  = Cs    + 524288;           // 6291456
    float* Pbuf  = outy  + 6291456;          // 1572864
    float* Qbuf  = Pbuf  + 1572864;          // 1572864  (total ~89 MB)

    const int BL = BB * LL;                  // 8192

    hipLaunchKernelGGL(k1_ln_inproj, dim3(BL), dim3(384), 0, stream,
                       x, y, ln_w, ln_b, in_proj, diff, xm, zbuf);
    hipLaunchKernelGGL(k2_conv, dim3(BL), dim3(DIN), 0, stream,
                       xm, conv_w, conv_b, xconv);
    hipLaunchKernelGGL(k3_xproj, dim3(BB*KD*LL), dim3(DIN), 0, stream,
                       xconv, x_proj, dt_w, dt_b, delta, Bs, Cs);
    hipLaunchKernelGGL(k4_scanA, dim3(BB*KD*NC), dim3(DIN), 0, stream,
                       xconv, delta, Bs, A_log, Pbuf, Qbuf);
    hipLaunchKernelGGL(k5_scanB, dim3((BB*KD*NST*DIN + 255)/256), dim3(256), 0, stream,
                       Pbuf, Qbuf);
    hipLaunchKernelGGL(k6_scanC, dim3(BB*KD*NC), dim3(DIN), 0, stream,
                       xconv, delta, Bs, Cs, A_log, Ds, Qbuf, outy);
    hipLaunchKernelGGL(k7_out, dim3(BL), dim3(DIN), 0, stream,
                       outy, zbuf, diff, onw, onb, out_w, out);
}

// Round 2
// 297.981 us; speedup vs baseline: 1.8536x; 1.8536x over previous
//
#include <hip/hip_runtime.h>
#include <math.h>

#define DIMC 96
#define DIN  192
#define NST  16
#define RNK  6
#define KD   4
#define HH   64
#define WWD  64
#define LL   4096
#define BB   2
#define NC   64    // number of chunks
#define CH   64    // chunk length (NC*CH == LL)

__device__ __forceinline__ int pos_of(int k, int l) {
    int t = ((l & 63) << 6) | (l >> 6);       // 64x64 transpose
    switch (k) {
        case 0: return l;
        case 1: return t;
        case 2: return LL - 1 - l;
        default: return ((((LL-1-l) & 63) << 6) | ((LL-1-l) >> 6));
    }
}

__device__ __forceinline__ float silu_f(float v) {
    return v / (1.f + expf(-v));
}

// ---------------- K0: transpose small weight matrices for coalesced GEMM staging ----------------
__global__ __launch_bounds__(256) void k0_prep(
    const float* __restrict__ Win, const float* __restrict__ Wout,
    const float* __restrict__ xpw,
    float* __restrict__ WinT, float* __restrict__ WoutT, float* __restrict__ xpwT)
{
    int idx = blockIdx.x*256 + threadIdx.x;
    int stride = gridDim.x*256;
    for (int i = idx; i < 96*384; i += stride) {          // WinT[j][o] = Win[o][j]
        int j = i / 384, o = i - j*384;
        WinT[i] = Win[o*96 + j];
    }
    for (int i = idx; i < 192*96; i += stride) {          // WoutT[j][o] = Wout[o][j]
        int j = i / 96, o = i - j*96;
        WoutT[i] = Wout[o*192 + j];
    }
    for (int i = idx; i < 4*192*40; i += stride) {        // xpwT[k][j][c], c padded to 40
        int kk = i / 7680; int rem = i - kk*7680;
        int j = rem / 40, c = rem - j*40;
        xpwT[i] = (c < RNK + 2*NST) ? xpw[((size_t)kk*(RNK+2*NST) + c)*DIN + j] : 0.f;
    }
}

// ---------------- K1: diff = |x-y|, LayerNorm(96), in_proj GEMM (8192x384x96) ----------------
// 32 positions/block, LDS-tiled: hT[j][pos] (stride 36), weight tile wl[j][128] (stride 132)
__global__ __launch_bounds__(256) void k1_ln_inproj(
    const float* __restrict__ x, const float* __restrict__ y,
    const float* __restrict__ lnw, const float* __restrict__ lnb,
    const float* __restrict__ WinT,
    float* __restrict__ diff, float* __restrict__ xm, float* __restrict__ zbuf)
{
    __shared__ float hT[96*36];
    __shared__ float wl[96*132];
    __shared__ float mu_s[32], rs_s[32];
    int t = threadIdx.x;
    int p0 = blockIdx.x * 32;

    // phase 1: |x-y|, write diff (coalesced), stage transposed in LDS
    #pragma unroll
    for (int s = 0; s < 12; s++) {
        int i = t + 256*s;
        float v = fabsf(x[(size_t)p0*96 + i] - y[(size_t)p0*96 + i]);
        diff[(size_t)p0*96 + i] = v;
        int pos = i / 96, ch = i - pos*96;
        hT[ch*36 + pos] = v;
    }
    __syncthreads();
    // LN reduce: 8 threads per position
    {
        int tg = t & 7, pos = t >> 3;
        float s1 = 0.f, s2 = 0.f;
        #pragma unroll
        for (int m = 0; m < 12; m++) {
            float v = hT[(tg + 8*m)*36 + pos];
            s1 += v; s2 += v*v;
        }
        s1 += __shfl_down(s1, 4, 8); s2 += __shfl_down(s2, 4, 8);
        s1 += __shfl_down(s1, 2, 8); s2 += __shfl_down(s2, 2, 8);
        s1 += __shfl_down(s1, 1, 8); s2 += __shfl_down(s2, 1, 8);
        if (tg == 0) {
            float mu = s1 * (1.f/96.f);
            float var = s2 * (1.f/96.f) - mu*mu;
            mu_s[pos] = mu; rs_s[pos] = rsqrtf(var + 1e-5f);
        }
    }
    __syncthreads();
    // normalize in place
    #pragma unroll
    for (int s = 0; s < 12; s++) {
        int i = t + 256*s;
        int pos = i / 96, ch = i - pos*96;
        float v = hT[ch*36 + pos];
        hT[ch*36 + pos] = (v - mu_s[pos]) * rs_s[pos] * lnw[ch] + lnb[ch];
    }

    // GEMM: 3 out-tiles of 128; thread = (o2 in 0..31 -> 4 outs, pg in 0..7 -> 4 pos)
    int o2 = t & 31, pg = t >> 5;
    for (int ot = 0; ot < 3; ot++) {
        __syncthreads();
        #pragma unroll
        for (int s = 0; s < 48; s++) {
            int i = t + 256*s;
            int j = i >> 7, ol = i & 127;
            wl[j*132 + ol] = WinT[j*384 + ot*128 + ol];
        }
        __syncthreads();
        float acc[4][4];
        #pragma unroll
        for (int a = 0; a < 4; a++)
            #pragma unroll
            for (int c = 0; c < 4; c++) acc[a][c] = 0.f;
        #pragma unroll 4
        for (int j = 0; j < 96; j++) {
            float wv[4], hv[4];
            *(float4*)wv = *(const float4*)&wl[j*132 + 4*o2];
            *(float4*)hv = *(const float4*)&hT[j*36 + 4*pg];
            #pragma unroll
            for (int pi = 0; pi < 4; pi++)
                #pragma unroll
                for (int c = 0; c < 4; c++) acc[pi][c] += hv[pi] * wv[c];
        }
        #pragma unroll
        for (int pi = 0; pi < 4; pi++) {
            int pos = p0 + 4*pg + pi;
            float4 val = make_float4(acc[pi][0], acc[pi][1], acc[pi][2], acc[pi][3]);
            int og = ot*128 + 4*o2;
            if (og < 192) *(float4*)&xm[(size_t)pos*192 + og] = val;
            else          *(float4*)&zbuf[(size_t)pos*192 + (og - 192)] = val;
        }
    }
}

// ---------------- K2: depthwise 3x3 conv + bias + SiLU ----------------
__global__ __launch_bounds__(192) void k2_conv(
    const float* __restrict__ xm, const float* __restrict__ cw,
    const float* __restrict__ cb, float* __restrict__ xconv)
{
    int p = blockIdx.x;            // b*L + l
    int d = threadIdx.x;
    int b = p >> 12;
    int l = p & (LL - 1);
    int hh = l >> 6, ww = l & 63;
    float acc = cb[d];
    const float* wd = cw + d*9;
    #pragma unroll
    for (int di = -1; di <= 1; di++) {
        int h2 = hh + di;
        if ((unsigned)h2 < HH) {
            #pragma unroll
            for (int dj = -1; dj <= 1; dj++) {
                int w2 = ww + dj;
                if ((unsigned)w2 < WWD)
                    acc += wd[(di+1)*3 + (dj+1)] * xm[((size_t)b*LL + h2*WWD + w2)*DIN + d];
            }
        }
    }
    xconv[(size_t)p*DIN + d] = silu_f(acc);
}

// ---------------- K3: x_proj GEMM + dt_proj + softplus, 32 pos/block ----------------
__global__ __launch_bounds__(256) void k3_xproj(
    const float* __restrict__ xconv, const float* __restrict__ xpwT,
    const float* __restrict__ dtw, const float* __restrict__ dtb,
    float* __restrict__ delta, float* __restrict__ Bs, float* __restrict__ Cs)
{
    __shared__ float uT[192*36];
    __shared__ float wx[192*40 + 64];   // slack for harmless OOB-row reads (discarded)
    __shared__ float xdl[32*40];
    int t = threadIdx.x;
    int blk = blockIdx.x;          // bk*128 + tile
    int tile = blk & 127, bk = blk >> 7;
    int k = bk & 3, b = bk >> 2;
    int c0 = tile*32;

    #pragma unroll
    for (int s = 0; s < 24; s++) {
        int i = t + 256*s;
        int pos = i / 192, ch = i - pos*192;
        int pp = pos_of(k, c0 + pos);
        uT[ch*36 + pos] = xconv[((size_t)b*LL + pp)*DIN + ch];
    }
    #pragma unroll
    for (int s = 0; s < 30; s++) {
        int i = t + 256*s;
        wx[i] = xpwT[(size_t)k*7680 + i];
    }
    __syncthreads();

    // GEMM1: xd[32 pos][40 c] ; thread: pq in 0..7 -> 4 pos, cg in 0..31 -> c = cg, cg+32
    int pq = t & 7, cg = t >> 3;
    float a0[4] = {0,0,0,0}, a1[4] = {0,0,0,0};
    #pragma unroll 4
    for (int j = 0; j < 192; j++) {
        float uv[4];
        *(float4*)uv = *(const float4*)&uT[j*36 + 4*pq];
        float w0 = wx[j*40 + cg];
        float w1 = wx[j*40 + cg + 32];
        #pragma unroll
        for (int pi = 0; pi < 4; pi++) { a0[pi] += uv[pi]*w0; a1[pi] += uv[pi]*w1; }
    }
    #pragma unroll
    for (int pi = 0; pi < 4; pi++) {
        xdl[(4*pq + pi)*40 + cg] = a0[pi];
        if (cg < 8) xdl[(4*pq + pi)*40 + cg + 32] = a1[pi];
    }
    __syncthreads();

    if (t < 192) {
        int d = t;
        float w6[RNK];
        #pragma unroll
        for (int r = 0; r < RNK; r++) w6[r] = dtw[((size_t)k*DIN + d)*RNK + r];
        float bias = dtb[k*DIN + d];
        for (int pp = 0; pp < 32; pp++) {
            float acc = bias;
            #pragma unroll
            for (int r = 0; r < RNK; r++) acc += xdl[pp*40 + r] * w6[r];
            float sp = (acc > 20.f) ? acc : log1pf(expf(acc));
            delta[((size_t)bk*LL + c0 + pp)*DIN + d] = sp;
        }
    } else {
        int q = t - 192;               // 0..63: 32 pos x 2 halves of 8 states
        int pp = q >> 1, half = q & 1;
        #pragma unroll
        for (int n8 = 0; n8 < 8; n8++) {
            int n = half*8 + n8;
            Bs[((size_t)bk*LL + c0 + pp)*NST + n] = xdl[pp*40 + RNK + n];
            Cs[((size_t)bk*LL + c0 + pp)*NST + n] = xdl[pp*40 + RNK + NST + n];
        }
    }
}

// ---------------- K4: scan pass A — per-chunk transfer ----------------
__global__ __launch_bounds__(192) void k4_scanA(
    const float* __restrict__ xconv, const float* __restrict__ delta,
    const float* __restrict__ BsArr, const float* __restrict__ A_log,
    float* __restrict__ P, float* __restrict__ Q)
{
    int blk = blockIdx.x;          // (b*K + k)*NC + c
    int c  = blk & (NC - 1);
    int bk = blk >> 6;
    int k  = bk & 3;
    int b  = bk >> 2;
    int d  = threadIdx.x;
    __shared__ float sB[CH][NST];
    for (int i = d; i < CH*NST; i += DIN) {
        int step = i >> 4, n = i & 15;
        sB[step][n] = BsArr[((size_t)bk*LL + c*CH + step)*NST + n];
    }
    float A[NST];
    #pragma unroll
    for (int n = 0; n < NST; n++) A[n] = -expf(A_log[((size_t)k*DIN + d)*NST + n]);
    __syncthreads();

    float h[NST], p[NST];
    #pragma unroll
    for (int n = 0; n < NST; n++) { h[n] = 0.f; p[n] = 1.f; }

    for (int step = 0; step < CH; step++) {
        int l = c*CH + step;
        float dl = delta[((size_t)bk*LL + l)*DIN + d];
        float uu = xconv[((size_t)b*LL + pos_of(k, l))*DIN + d];
        float du = dl * uu;
        #pragma unroll
        for (int n = 0; n < NST; n++) {
            float a = __expf(dl * A[n]);
            h[n] = a*h[n] + du*sB[step][n];
            p[n] *= a;
        }
    }
    size_t base = (size_t)blk*NST*DIN + d;
    #pragma unroll
    for (int n = 0; n < NST; n++) { P[base + n*DIN] = p[n]; Q[base + n*DIN] = h[n]; }
}

// ---------------- K5: scan pass B — compose chunk transfers ----------------
__global__ __launch_bounds__(256) void k5_scanB(
    const float* __restrict__ P, float* __restrict__ Q)
{
    int idx = blockIdx.x*256 + threadIdx.x;      // 24576 = B*K*N*Din
    if (idx >= BB*KD*NST*DIN) return;
    int d = idx % DIN;
    int rest = idx / DIN;
    int n = rest % NST; rest /= NST;
    int k = rest % KD;
    int b = rest / KD;
    size_t base = ((((size_t)(b*KD + k))*NC)*NST + n)*DIN + d;
    size_t stride = (size_t)NST*DIN;
    float h = 0.f;
    for (int c = 0; c < NC; c++) {
        float p = P[base + c*stride];
        float q = Q[base + c*stride];
        Q[base + c*stride] = h;
        h = p*h + q;
    }
}

// ---------------- K6: scan pass C — replay with init state, emit y ----------------
__global__ __launch_bounds__(192) void k6_scanC(
    const float* __restrict__ xconv, const float* __restrict__ delta,
    const float* __restrict__ BsArr, const float* __restrict__ CsArr,
    const float* __restrict__ A_log, const float* __restrict__ Ds,
    const float* __restrict__ Q, float* __restrict__ outy)
{
    int blk = blockIdx.x;
    int c  = blk & (NC - 1);
    int bk = blk >> 6;
    int k  = bk & 3;
    int b  = bk >> 2;
    int d  = threadIdx.x;
    __shared__ float sB[CH][NST];
    __shared__ float sC[CH][NST];
    for (int i = d; i < CH*NST; i += DIN) {
        int step = i >> 4, n = i & 15;
        sB[step][n] = BsArr[((size_t)bk*LL + c*CH + step)*NST + n];
        sC[step][n] = CsArr[((size_t)bk*LL + c*CH + step)*NST + n];
    }
    float A[NST];
    #pragma unroll
    for (int n = 0; n < NST; n++) A[n] = -expf(A_log[((size_t)k*DIN + d)*NST + n]);
    float h[NST];
    size_t base = (size_t)blk*NST*DIN + d;
    #pragma unroll
    for (int n = 0; n < NST; n++) h[n] = Q[base + n*DIN];
    float Dv = Ds[k*DIN + d];
    __syncthreads();

    for (int step = 0; step < CH; step++) {
        int l = c*CH + step;
        float dl = delta[((size_t)bk*LL + l)*DIN + d];
        float uu = xconv[((size_t)b*LL + pos_of(k, l))*DIN + d];
        float du = dl * uu;
        float yv = 0.f;
        #pragma unroll
        for (int n = 0; n < NST; n++) {
            float a = __expf(dl * A[n]);
            h[n] = a*h[n] + du*sB[step][n];
            yv += h[n] * sC[step][n];
        }
        outy[((size_t)bk*LL + l)*DIN + d] = yv + Dv*uu;
    }
}

// ---------------- K7: combine 4 dirs, LN(192), gate, out_proj GEMM, residual ----------------
__global__ __launch_bounds__(256) void k7_out(
    const float* __restrict__ outy, const float* __restrict__ zbuf,
    const float* __restrict__ diff, const float* __restrict__ onw,
    const float* __restrict__ onb, const float* __restrict__ WoutT,
    float* __restrict__ out)
{
    __shared__ float gT[192*36];
    __shared__ float wl[192*96];
    __shared__ float mu_s[32], rs_s[32];
    int t = threadIdx.x;
    int p0 = blockIdx.x*32;
    int b = p0 >> 12;
    int l0 = p0 & (LL - 1);

    #pragma unroll
    for (int s = 0; s < 72; s++) {
        int i = t + 256*s;
        wl[i] = WoutT[i];                     // WoutT is 192*96, contiguous
    }
    #pragma unroll
    for (int s = 0; s < 24; s++) {
        int i = t + 256*s;
        int pos = i / 192, ch = i - pos*192;
        int l = l0 + pos;
        int tl = ((l & 63) << 6) | (l >> 6);
        float yc = outy[(((size_t)(b*KD + 0))*LL + l)*DIN + ch]
                 + outy[(((size_t)(b*KD + 2))*LL + (LL-1-l))*DIN + ch]
                 + outy[(((size_t)(b*KD + 1))*LL + tl)*DIN + ch]
                 + outy[(((size_t)(b*KD + 3))*LL + (LL-1-tl))*DIN + ch];
        gT[ch*36 + pos] = yc;
    }
    __syncthreads();
    {
        int tg = t & 7, pos = t >> 3;
        float s1 = 0.f, s2 = 0.f;
        #pragma unroll
        for (int m = 0; m < 24; m++) {
            float v = gT[(tg + 8*m)*36 + pos];
            s1 += v; s2 += v*v;
        }
        s1 += __shfl_down(s1, 4, 8); s2 += __shfl_down(s2, 4, 8);
        s1 += __shfl_down(s1, 2, 8); s2 += __shfl_down(s2, 2, 8);
        s1 += __shfl_down(s1, 1, 8); s2 += __shfl_down(s2, 1, 8);
        if (tg == 0) {
            float mu = s1 * (1.f/192.f);
            float var = s2 * (1.f/192.f) - mu*mu;
            mu_s[pos] = mu; rs_s[pos] = rsqrtf(var + 1e-5f);
        }
    }
    __syncthreads();
    #pragma unroll
    for (int s = 0; s < 24; s++) {
        int i = t + 256*s;
        int pos = i / 192, ch = i - pos*192;
        float v = gT[ch*36 + pos];
        float yn = (v - mu_s[pos]) * rs_s[pos] * onw[ch] + onb[ch];
        float z = zbuf[(size_t)(p0 + pos)*DIN + ch];
        gT[ch*36 + pos] = yn * silu_f(z);
    }
    __syncthreads();

    // GEMM: 96 outs; thread: o1 in 0..31 -> outs {o1, o1+32, o1+64}, pg -> 4 pos
    int o1 = t & 31, pg = t >> 5;
    float acc[4][3];
    #pragma unroll
    for (int a = 0; a < 4; a++) { acc[a][0] = 0.f; acc[a][1] = 0.f; acc[a][2] = 0.f; }
    #pragma unroll 4
    for (int j = 0; j < 192; j++) {
        float hv[4];
        *(float4*)hv = *(const float4*)&gT[j*36 + 4*pg];
        float w0 = wl[j*96 + o1];
        float w1 = wl[j*96 + o1 + 32];
        float w2 = wl[j*96 + o1 + 64];
        #pragma unroll
        for (int pi = 0; pi < 4; pi++) {
            acc[pi][0] += hv[pi]*w0;
            acc[pi][1] += hv[pi]*w1;
            acc[pi][2] += hv[pi]*w2;
        }
    }
    #pragma unroll
    for (int pi = 0; pi < 4; pi++) {
        size_t p = (size_t)(p0 + 4*pg + pi);
        out[p*DIMC + o1]      = acc[pi][0] + diff[p*DIMC + o1];
        out[p*DIMC + o1 + 32] = acc[pi][1] + diff[p*DIMC + o1 + 32];
        out[p*DIMC + o1 + 64] = acc[pi][2] + diff[p*DIMC + o1 + 64];
    }
}

extern "C" void kernel_launch(void* const* d_in, const int* in_sizes, int n_in,
                              void* d_out, int out_size, void* d_ws, size_t ws_size,
                              hipStream_t stream)
{
    const float* x       = (const float*)d_in[0];
    const float* y       = (const float*)d_in[1];
    const float* ln_w    = (const float*)d_in[2];
    const float* ln_b    = (const float*)d_in[3];
    const float* in_proj = (const float*)d_in[4];
    const float* conv_w  = (const float*)d_in[5];
    const float* conv_b  = (const float*)d_in[6];
    const float* x_proj  = (const float*)d_in[7];
    const float* dt_w    = (const float*)d_in[8];
    const float* dt_b    = (const float*)d_in[9];
    const float* A_log   = (const float*)d_in[10];
    const float* Ds      = (const float*)d_in[11];
    const float* onw     = (const float*)d_in[12];
    const float* onb     = (const float*)d_in[13];
    const float* out_w   = (const float*)d_in[14];
    float* out = (float*)d_out;

    float* ws    = (float*)d_ws;
    float* diff  = ws;                       // 786432
    float* zbuf  = diff  + 786432;           // 1572864
    float* xm    = zbuf  + 1572864;          // 1572864
    float* xconv = xm    + 1572864;          // 1572864
    float* delta = xconv + 1572864;          // 6291456
    float* Bs    = delta + 6291456;          // 524288
    float* Cs    = Bs    + 524288;           // 524288
    float* outy  = Cs    + 524288;           // 6291456
    float* Pbuf  = outy  + 6291456;          // 1572864
    float* Qbuf  = Pbuf  + 1572864;          // 1572864
    float* WinT  = Qbuf  + 1572864;          // 36864
    float* WoutT = WinT  + 36864;            // 18432
    float* xpwT  = WoutT + 18432;            // 30720   (total ~89.5 MB)

    const int BL = BB * LL;                  // 8192

    hipLaunchKernelGGL(k0_prep, dim3(144), dim3(256), 0, stream,
                       in_proj, out_w, x_proj, WinT, WoutT, xpwT);
    hipLaunchKernelGGL(k1_ln_inproj, dim3(BL/32), dim3(256), 0, stream,
                       x, y, ln_w, ln_b, WinT, diff, xm, zbuf);
    hipLaunchKernelGGL(k2_conv, dim3(BL), dim3(DIN), 0, stream,
                       xm, conv_w, conv_b, xconv);
    hipLaunchKernelGGL(k3_xproj, dim3(BB*KD*128), dim3(256), 0, stream,
                       xconv, xpwT, dt_w, dt_b, delta, Bs, Cs);
    hipLaunchKernelGGL(k4_scanA, dim3(BB*KD*NC), dim3(DIN), 0, stream,
                       xconv, delta, Bs, A_log, Pbuf, Qbuf);
    hipLaunchKernelGGL(k5_scanB, dim3((BB*KD*NST*DIN + 255)/256), dim3(256), 0, stream,
                       Pbuf, Qbuf);
    hipLaunchKernelGGL(k6_scanC, dim3(BB*KD*NC), dim3(DIN), 0, stream,
                       xconv, delta, Bs, Cs, A_log, Ds, Qbuf, outy);
    hipLaunchKernelGGL(k7_out, dim3(BL/32), dim3(256), 0, stream,
                       outy, zbuf, diff, onw, onb, WoutT, out);
}